// Round 5
// baseline (321.658 us; speedup 1.0000x reference)
//
#include <hip/hip_runtime.h>

#define ALPHA_MIN 0.8187307530779818f  // exp(-1/5)
#define ALPHA_MAX 0.9607894391523232f  // exp(-1/25)

typedef _Float16 f16;
typedef _Float16 f16x8 __attribute__((ext_vector_type(8)));
typedef float f32x16 __attribute__((ext_vector_type(16)));

// Fixed problem shape (reference setup)
#define BB_ 32
#define TT_ 2048
#define KK_ 256
#define HH_ 512
#define TC_ 64               // timesteps per chunk
#define NC_ (TT_ / TC_)      // 32 chunks
#define NB_ 64               // h-cols per block

// ============================ fused kernel ==================================
// grid = 256 = (nt<<5)|b  (8 n-panels of one batch share an XCD -> L2 reuse
// of X[b]).  block = 320 threads = 5 waves:
//   waves 0-3: GEMM  (Wx chunk tile 64x64, each wave one 32x32 MFMA tile,
//              fp16-split: C = Ah*Bh + 2^-11*(Ah*Bl + Al*Bh), W-panel frags
//              held in REGISTERS -> k-loop has no LDS, no barrier)
//   wave  4 : LIF scan over the chunk stream (64 h-chains), consumes chunk
//             c-1 from LDS while GEMM produces chunk c (double buffer).
__global__ __launch_bounds__(320, 2) void lif_fused(
    const float* __restrict__ X,      // (B,T,K)
    const float* __restrict__ W,      // (H,K)
    const float* __restrict__ alpha,  // (H)
    const float* __restrict__ u0,     // (B,H)
    const float* __restrict__ s0,     // (B,H)
    float* __restrict__ out)          // (B,T,H)
{
    __shared__ float wxbuf[2][TC_ * NB_];   // 2 x 16 KB

    const int b  = blockIdx.x & 31;
    const int nt = blockIdx.x >> 5;
    const int n0 = nt * NB_;

    const int tid  = threadIdx.x;
    const int wv   = tid >> 6;
    const int lane = tid & 63;
    const int fm   = lane & 31;
    const int fq   = lane >> 5;

    if (wv < 4) {
        // ------------------------- GEMM waves ------------------------------
        const int mh = wv >> 1;           // m-half within 64-row chunk
        const int nh = wv & 1;            // n-half within 64-col panel
        const int ncol = n0 + nh * 32 + fm;

        // B prologue: W[ncol][0..256) -> hi/lo f16 fragments in registers
        f16x8 bh[16], bl[16];
        {
            const float* wp = W + (size_t)ncol * KK_ + fq * 8;
#pragma unroll
            for (int ks = 0; ks < 16; ++ks) {
                float4 v0 = *(const float4*)(wp + ks * 16);
                float4 v1 = *(const float4*)(wp + ks * 16 + 4);
                float v[8] = {v0.x, v0.y, v0.z, v0.w, v1.x, v1.y, v1.z, v1.w};
                f16x8 h, l;
#pragma unroll
                for (int j = 0; j < 8; ++j) {
                    const f16 hj = (f16)v[j];
                    h[j] = hj;
                    l[j] = (f16)((v[j] - (float)hj) * 2048.0f);
                }
                bh[ks] = h; bl[ks] = l;
            }
        }

        f32x16 accH, accL;
#pragma unroll
        for (int e = 0; e < 16; ++e) { accH[e] = 0.0f; accL[e] = 0.0f; }

        // A row for this lane in chunk c: t = c*64 + mh*32 + fm
        const float* xrow = X + ((size_t)b * TT_ + mh * 32 + fm) * KK_ + fq * 8;

        // rolling 4-deep prefetch over flat k-index ki = c*16 + ks
        float4 abuf[4][2];
        auto pref = [&](int ki) {
            if (ki < NC_ * 16) {
                const float* p = xrow + (size_t)(ki >> 4) * (TC_ * KK_) + (ki & 15) * 16;
                abuf[ki & 3][0] = *(const float4*)p;
                abuf[ki & 3][1] = *(const float4*)(p + 4);
            }
        };
        pref(0); pref(1); pref(2); pref(3);

        for (int c = 0; c < NC_; ++c) {
            int ki = c * 16;
#pragma unroll
            for (int ks = 0; ks < 16; ++ks, ++ki) {
                const float4 a0 = abuf[ki & 3][0];
                const float4 a1 = abuf[ki & 3][1];
                pref(ki + 4);
                const float v[8] = {a0.x, a0.y, a0.z, a0.w, a1.x, a1.y, a1.z, a1.w};
                f16x8 ah, al;
#pragma unroll
                for (int j = 0; j < 8; ++j) {
                    const f16 hj = (f16)v[j];
                    ah[j] = hj;
                    al[j] = (f16)((v[j] - (float)hj) * 2048.0f);
                }
                accH = __builtin_amdgcn_mfma_f32_32x32x16_f16(ah, bh[ks], accH, 0, 0, 0);
                accL = __builtin_amdgcn_mfma_f32_32x32x16_f16(ah, bl[ks], accL, 0, 0, 0);
                accL = __builtin_amdgcn_mfma_f32_32x32x16_f16(al, bh[ks], accL, 0, 0, 0);
            }
            // epilogue: 32x32 tile -> wxbuf[c&1]
            // C/D layout: col = lane&31, row = (r&3) + 8*(r>>2) + 4*(lane>>5)
            float* wb = &wxbuf[c & 1][0];
#pragma unroll
            for (int r = 0; r < 16; ++r) {
                const int row = mh * 32 + (r & 3) + 8 * (r >> 2) + 4 * fq;
                wb[row * NB_ + nh * 32 + fm] = accH[r] + accL[r] * (1.0f / 2048.0f);
                accH[r] = 0.0f; accL[r] = 0.0f;
            }
            __syncthreads();
        }
    } else {
        // ------------------------- scan wave -------------------------------
        const int h = n0 + lane;
        const int chain = b * HH_ + h;
        float a = alpha[h];
        a = fminf(fmaxf(a, ALPHA_MIN), ALPHA_MAX);
        const float bbv = 1.0f - a;
        float u = u0[chain];
        float s = s0[chain];
        float* op = out + (size_t)b * TT_ * HH_ + h;

        for (int c = 0; c < NC_; ++c) {
            if (c > 0) {
                const float* wb = &wxbuf[(c - 1) & 1][0];
                const int tbase = (c - 1) * TC_;
                for (int t0 = 0; t0 < TC_; t0 += 8) {
                    float w[8];
#pragma unroll
                    for (int j = 0; j < 8; ++j) w[j] = wb[(t0 + j) * NB_ + lane];
#pragma unroll
                    for (int j = 0; j < 8; ++j) {
                        u = fmaf(a, u - s, bbv * w[j]);
                        s = (u > 1.0f) ? 1.0f : 0.0f;
                        __builtin_nontemporal_store(s, &op[(size_t)(tbase + t0 + j) * HH_]);
                    }
                }
            }
            __syncthreads();
        }
        // final chunk
        {
            const float* wb = &wxbuf[(NC_ - 1) & 1][0];
            const int tbase = (NC_ - 1) * TC_;
            for (int t0 = 0; t0 < TC_; t0 += 8) {
                float w[8];
#pragma unroll
                for (int j = 0; j < 8; ++j) w[j] = wb[(t0 + j) * NB_ + lane];
#pragma unroll
                for (int j = 0; j < 8; ++j) {
                    u = fmaf(a, u - s, bbv * w[j]);
                    s = (u > 1.0f) ? 1.0f : 0.0f;
                    __builtin_nontemporal_store(s, &op[(size_t)(tbase + t0 + j) * HH_]);
                }
            }
        }
    }
}

// =================== generic fallback (never hit for ref shape) =============
__global__ void gemm_naive(const float* __restrict__ X, const float* __restrict__ W,
                           float* __restrict__ C, int M, int N, int K)
{
    const int idx = blockIdx.x * 256 + threadIdx.x;
    if (idx >= M * N) return;
    const int m = idx / N, n = idx % N;
    float acc = 0.0f;
    for (int k = 0; k < K; ++k) acc = fmaf(X[(size_t)m * K + k], W[(size_t)n * K + k], acc);
    C[idx] = acc;
}

__global__ __launch_bounds__(64) void lif_scan_inplace(
    float* __restrict__ buf, const float* __restrict__ alpha,
    const float* __restrict__ u0, const float* __restrict__ s0, int T, int H)
{
    const int chain = blockIdx.x * 64 + threadIdx.x;
    const int h = chain % H;
    const int b = chain / H;
    float a = alpha[h];
    a = fminf(fmaxf(a, ALPHA_MIN), ALPHA_MAX);
    const float bb = 1.0f - a;
    float u = u0[chain], s = s0[chain];
    float* base = buf + (size_t)b * T * H + h;
    for (int t = 0; t < T; ++t) {
        u = fmaf(a, u - s, bb * base[(size_t)t * H]);
        s = (u > 1.0f) ? 1.0f : 0.0f;
        base[(size_t)t * H] = s;
    }
}

// ---------------- launch ----------------------------------------------------
extern "C" void kernel_launch(void* const* d_in, const int* in_sizes, int n_in,
                              void* d_out, int out_size, void* d_ws, size_t ws_size,
                              hipStream_t stream) {
    const float* x     = (const float*)d_in[0];
    const float* W     = (const float*)d_in[1];
    const float* alpha = (const float*)d_in[2];
    const float* u0    = (const float*)d_in[3];
    const float* s0    = (const float*)d_in[4];
    float* out = (float*)d_out;

    const int H = in_sizes[2];
    const int I = in_sizes[1] / H;
    const int B = in_sizes[3] / H;
    const int T = in_sizes[0] / (B * I);

    if (B == BB_ && T == TT_ && I == KK_ && H == HH_) {
        lif_fused<<<256, 320, 0, stream>>>(x, W, alpha, u0, s0, out);
    } else {
        const int M = B * T;
        gemm_naive<<<(M * H + 255) / 256, 256, 0, stream>>>(x, W, out, M, H, I);
        lif_scan_inplace<<<(B * H + 63) / 64, 64, 0, stream>>>(out, alpha, u0, s0, T, H);
    }
}